// Round 11
// baseline (755.538 us; speedup 1.0000x reference)
//
#include <hip/hip_runtime.h>
#include <hip/hip_bf16.h>

#define N_TOK 2048
#define H_DIM 2048
#define V_DIM 32000

typedef __attribute__((ext_vector_type(8))) short short8;
typedef __attribute__((ext_vector_type(4))) short s16x4;
typedef __attribute__((ext_vector_type(4))) float f32x4;

__device__ __forceinline__ float bf2f(short s) {
  unsigned int u = ((unsigned int)(unsigned short)s) << 16;
  return __uint_as_float(u);
}
__device__ __forceinline__ short f2b(float f) {
  __hip_bfloat16 h = __float2bfloat16(f);
  return *reinterpret_cast<short*>(&h);
}

// ---------------- fp32 -> bf16 conversion (activations only, 40 MB) -------
__global__ __launch_bounds__(256) void cvt_in(const float* __restrict__ s0,
                                              const float* __restrict__ s1,
                                              short* __restrict__ d0,
                                              short* __restrict__ d1) {
  const int b = blockIdx.x;
  const float* s = (b < 256) ? s0 : s1;
  short* d = (b < 256) ? d0 : d1;
  const int b0 = b & 255;
  const int n8 = N_TOK * H_DIM / 8;
  for (int i = b0 * 256 + threadIdx.x; i < n8; i += 256 * 256) {
    const float4* sp = reinterpret_cast<const float4*>(s) + (size_t)i * 2;
    float4 a = sp[0], c = sp[1];
    short8 o;
    o[0] = f2b(a.x); o[1] = f2b(a.y); o[2] = f2b(a.z); o[3] = f2b(a.w);
    o[4] = f2b(c.x); o[5] = f2b(c.y); o[6] = f2b(c.z); o[7] = f2b(c.w);
    *reinterpret_cast<short8*>(d + (size_t)i * 8) = o;
  }
}

// ---------------- GEMM: logits[n,v] = sum_h A[n,h]*W[v,h], W fp32 direct --
// FROZEN r8 skeleton (16x16x32, 0 bank conflicts, 1 end-barrier/phase).
// W is read as fp32 and converted in-kernel (saves the 768 MB cvt round
// trip). Per tile t:
//   P1: stage A0,A2(t+1)->nbase (gload_lds).
//   P2: stage A1,A3(t+1)->nbase.
//   P3 (the empty phase): cvt br (Bf32(t+1), issued P3(t-1), 4-phase
//       window) -> ds_write bf16 into nbase B region (region last read at
//       P3(t-1), published); then issue 8 Bf32(t+2) loads into br.
//   P4: end gate vmcnt(8): completes A(t+1) (4 oldest), leaves the 8
//       Bf32(t+2) in flight across the tile boundary.
#define ASH 16384      // A shorts per buffer (256 rows x 64 cols)
#define BUF_SH 32768   // shorts per buffer (A + B)

__device__ __forceinline__ void gload_lds16(const void* g, void* l) {
  __builtin_amdgcn_global_load_lds(
      (const __attribute__((address_space(1))) void*)g,
      (__attribute__((address_space(3))) void*)l, 16, 0, 0);
}

#define STAGE_A(i, dst, kb) \
  gload_lds16(Aby + aoff##i + (kb), &lds[(dst) + (i) * 4096 + wbase])

// Load the 2 fp32 dwordx4 for B granule-slot i into br (plain loads -> regs).
#define BLOAD(i, kbF) \
  br[2*(i)]   = *(const f32x4*)(Wby + boffF##i + (kbF)); \
  br[2*(i)+1] = *(const f32x4*)(Wby + boffF##i + (kbF) + 16);
// Convert & write B granule-slot i to LDS (linear lane-consecutive 16 B,
// identical __float2bfloat16 rounding as the old cvt pass).
#define CVTWR(i, dst) { short8 pk;                                             \
    pk[0] = f2b(br[2*(i)][0]);   pk[1] = f2b(br[2*(i)][1]);                    \
    pk[2] = f2b(br[2*(i)][2]);   pk[3] = f2b(br[2*(i)][3]);                    \
    pk[4] = f2b(br[2*(i)+1][0]); pk[5] = f2b(br[2*(i)+1][1]);                  \
    pk[6] = f2b(br[2*(i)+1][2]); pk[7] = f2b(br[2*(i)+1][3]);                  \
    *(short8*)&lds[(dst) + ASH + (i) * 4096 + wbase + lane * 8] = pk; }

#define PHASE(KK, MH, GATE, ...) do {                                          \
    const int xorc = (((KK) * 4 + lk) ^ lr7) << 3;                             \
    short8 av0 = *(const short8*)&lds[cbase + aro + (MH)*4096 + 0    + xorc];  \
    short8 av1 = *(const short8*)&lds[cbase + aro + (MH)*4096 + 1024 + xorc];  \
    short8 av2 = *(const short8*)&lds[cbase + aro + (MH)*4096 + 2048 + xorc];  \
    short8 av3 = *(const short8*)&lds[cbase + aro + (MH)*4096 + 3072 + xorc];  \
    if ((MH) == 0) {                                                           \
      bv[0] = *(const short8*)&lds[cbase + bro + 0    + xorc];                 \
      bv[1] = *(const short8*)&lds[cbase + bro + 1024 + xorc];                 \
      bv[2] = *(const short8*)&lds[cbase + bro + 2048 + xorc];                 \
      bv[3] = *(const short8*)&lds[cbase + bro + 3072 + xorc];                 \
    }                                                                          \
    __VA_ARGS__                                                                \
    asm volatile("s_waitcnt lgkmcnt(0)" ::: "memory");                         \
    __builtin_amdgcn_sched_barrier(0);                                         \
    __builtin_amdgcn_s_setprio(1);                                             \
    acc[(MH)*4+0][0] = __builtin_amdgcn_mfma_f32_16x16x32_bf16(av0, bv[0], acc[(MH)*4+0][0],0,0,0); \
    acc[(MH)*4+0][1] = __builtin_amdgcn_mfma_f32_16x16x32_bf16(av0, bv[1], acc[(MH)*4+0][1],0,0,0); \
    acc[(MH)*4+0][2] = __builtin_amdgcn_mfma_f32_16x16x32_bf16(av0, bv[2], acc[(MH)*4+0][2],0,0,0); \
    acc[(MH)*4+0][3] = __builtin_amdgcn_mfma_f32_16x16x32_bf16(av0, bv[3], acc[(MH)*4+0][3],0,0,0); \
    acc[(MH)*4+1][0] = __builtin_amdgcn_mfma_f32_16x16x32_bf16(av1, bv[0], acc[(MH)*4+1][0],0,0,0); \
    acc[(MH)*4+1][1] = __builtin_amdgcn_mfma_f32_16x16x32_bf16(av1, bv[1], acc[(MH)*4+1][1],0,0,0); \
    acc[(MH)*4+1][2] = __builtin_amdgcn_mfma_f32_16x16x32_bf16(av1, bv[2], acc[(MH)*4+1][2],0,0,0); \
    acc[(MH)*4+1][3] = __builtin_amdgcn_mfma_f32_16x16x32_bf16(av1, bv[3], acc[(MH)*4+1][3],0,0,0); \
    acc[(MH)*4+2][0] = __builtin_amdgcn_mfma_f32_16x16x32_bf16(av2, bv[0], acc[(MH)*4+2][0],0,0,0); \
    acc[(MH)*4+2][1] = __builtin_amdgcn_mfma_f32_16x16x32_bf16(av2, bv[1], acc[(MH)*4+2][1],0,0,0); \
    acc[(MH)*4+2][2] = __builtin_amdgcn_mfma_f32_16x16x32_bf16(av2, bv[2], acc[(MH)*4+2][2],0,0,0); \
    acc[(MH)*4+2][3] = __builtin_amdgcn_mfma_f32_16x16x32_bf16(av2, bv[3], acc[(MH)*4+2][3],0,0,0); \
    acc[(MH)*4+3][0] = __builtin_amdgcn_mfma_f32_16x16x32_bf16(av3, bv[0], acc[(MH)*4+3][0],0,0,0); \
    acc[(MH)*4+3][1] = __builtin_amdgcn_mfma_f32_16x16x32_bf16(av3, bv[1], acc[(MH)*4+3][1],0,0,0); \
    acc[(MH)*4+3][2] = __builtin_amdgcn_mfma_f32_16x16x32_bf16(av3, bv[2], acc[(MH)*4+3][2],0,0,0); \
    acc[(MH)*4+3][3] = __builtin_amdgcn_mfma_f32_16x16x32_bf16(av3, bv[3], acc[(MH)*4+3][3],0,0,0); \
    __builtin_amdgcn_s_setprio(0);                                             \
    if ((GATE) == 8) asm volatile("s_waitcnt vmcnt(8)" ::: "memory");          \
    if ((GATE) == 0) asm volatile("s_waitcnt vmcnt(0)" ::: "memory");          \
    __builtin_amdgcn_sched_barrier(0);                                         \
    __builtin_amdgcn_s_barrier();                                              \
  } while (0)

__global__ __launch_bounds__(512, 2) void gemm_logits(
    const short* __restrict__ As, const short* __restrict__ At,
    const float* __restrict__ Wsf, const float* __restrict__ Wtf,
    unsigned long long* __restrict__ Lgs, unsigned long long* __restrict__ Lgt,
    float* __restrict__ Zpart) {
  __shared__ short lds[2 * BUF_SH];  // 128 KiB

  // XCD chunking + mblk-fastest: the 8 sharers of one 2 MB fp32 W panel run
  // inside one chunk -> one XCD's L2; W streams HBM ~once.
  const int gid = blockIdx.x;
  const int swz = (gid & 7) * 250 + (gid >> 3);
  const int gemm = swz >= 1000;
  const int rem = swz - gemm * 1000;
  const int vblk = rem >> 3, mblk = rem & 7;
  const short* A = gemm ? At : As;
  unsigned long long* Lp = gemm ? Lgt : Lgs;
  const int m0 = mblk * 256, v0 = vblk * 256;

  const int tid = threadIdx.x;
  const int wave = tid >> 6, lane = tid & 63;
  const int lrow = lane & 15, lk = lane >> 4, lr7 = lrow & 7;
  const int wr = wave >> 2, wc = wave & 3;
  const int wbase = wave * 512;
  const int aro = (wr * 128 + lrow) * 64;
  const int bro = ASH + (wc * 64 + lrow) * 64;
  const char* Aby = (const char*)A;
  const char* Wby = (const char*)(gemm ? Wtf : Wsf);

  // Pre-swizzled per-lane source offsets: A bf16 bytes (kb = t*128),
  // B fp32 bytes (kbF = t*256).
  unsigned aoff0, aoff1, aoff2, aoff3, boffF0, boffF1, boffF2, boffF3;
  {
#define MKOFF(i, dstA, dstB)                                                   \
    {                                                                          \
      int g = (i) * 512 + wave * 64 + lane;                                    \
      int row = g >> 3, c8p = g & 7, col = (c8p ^ (row & 7)) << 3;             \
      dstA = (unsigned)((((m0) + row) * H_DIM + col) * 2);                     \
      dstB = (unsigned)((((v0) + row) * H_DIM + col) * 4);                     \
    }
    MKOFF(0, aoff0, boffF0) MKOFF(1, aoff1, boffF1)
    MKOFF(2, aoff2, boffF2) MKOFF(3, aoff3, boffF3)
#undef MKOFF
  }

  f32x4 acc[8][4];
#pragma unroll
  for (int i = 0; i < 8; ++i)
#pragma unroll
    for (int j = 0; j < 4; ++j) acc[i][j] = (f32x4){0.f, 0.f, 0.f, 0.f};
  short8 bv[4];
  f32x4 br[8];  // in-flight fp32 B tile (consumed P3(t), reloaded P3(t))

  // Prologue: Bf32(t0)->br; A(t0) x4 gloads; cvt B(t0)->buf0 (auto-waits
  // br); Bf32(t1)->br; gate vmcnt(8): A(t0) landed, Bf32(t1) 8 in flight.
  BLOAD(0, 0); BLOAD(1, 0); BLOAD(2, 0); BLOAD(3, 0);
  STAGE_A(0, 0, 0); STAGE_A(2, 0, 0); STAGE_A(1, 0, 0); STAGE_A(3, 0, 0);
  CVTWR(0, 0); CVTWR(1, 0); CVTWR(2, 0); CVTWR(3, 0);
  BLOAD(0, 256); BLOAD(1, 256); BLOAD(2, 256); BLOAD(3, 256);
  asm volatile("s_waitcnt vmcnt(8)" ::: "memory");
  asm volatile("s_waitcnt lgkmcnt(0)" ::: "memory");
  __builtin_amdgcn_sched_barrier(0);
  __builtin_amdgcn_s_barrier();

  // Steady tiles 0..29.
  for (int t = 0; t < 30; ++t) {
    const int cbase = (t & 1) * BUF_SH, nbase = cbase ^ BUF_SH;
    const int kbn = (t + 1) * 128;
    const int kbF2 = (t + 2) * 256;
    PHASE(0, 0, -1, STAGE_A(0, nbase, kbn); STAGE_A(2, nbase, kbn););
    PHASE(0, 1, -1, STAGE_A(1, nbase, kbn); STAGE_A(3, nbase, kbn););
    PHASE(1, 0, -1, CVTWR(0, nbase); CVTWR(1, nbase);
                    CVTWR(2, nbase); CVTWR(3, nbase);
                    BLOAD(0, kbF2); BLOAD(1, kbF2);
                    BLOAD(2, kbF2); BLOAD(3, kbF2););
    PHASE(1, 1,  8, (void)0;);
  }
  // Tile 30: stage A(31), cvt B(31); drain A(31) at the gate.
  { const int cbase = 0, nbase = BUF_SH, kbn = 31 * 128;
    PHASE(0, 0, -1, STAGE_A(0, nbase, kbn); STAGE_A(2, nbase, kbn););
    PHASE(0, 1, -1, STAGE_A(1, nbase, kbn); STAGE_A(3, nbase, kbn););
    PHASE(1, 0, -1, CVTWR(0, nbase); CVTWR(1, nbase);
                    CVTWR(2, nbase); CVTWR(3, nbase););
    PHASE(1, 1,  0, (void)0;);
  }
  // Tile 31: pure compute.
  { const int cbase = BUF_SH;
    PHASE(0, 0, -1, (void)0;);
    PHASE(0, 1, -1, (void)0;);
    PHASE(1, 0, -1, (void)0;);
    PHASE(1, 1, -1, (void)0;);
  }

  // ---- Epilogue A: per-row sum-of-exp over this wave's 64 columns --------
  {
    const int q = lane >> 4;
    const int zb = (gemm * 2048 + mblk * 256 + wr * 128) * 500 + vblk * 4 + wc;
#pragma unroll
    for (int fm = 0; fm < 8; ++fm) {
#pragma unroll
      for (int j = 0; j < 4; ++j) {
        float s = __expf(acc[fm][0][j]) + __expf(acc[fm][1][j]) +
                  __expf(acc[fm][2][j]) + __expf(acc[fm][3][j]);
        s += __shfl_xor(s, 8);
        s += __shfl_xor(s, 4);
        s += __shfl_xor(s, 2);
        s += __shfl_xor(s, 1);
        if ((lane & 15) == 0)
          Zpart[zb + (fm * 16 + q * 4 + j) * 500] = s;
      }
    }
  }

  // ---- Epilogue B: pack-layout bf16 logits store (r5-verified) -----------
  const size_t pkb = ((size_t)(mblk * 125 + vblk) * 8 + wave) * 2048 + lane;
  s16x4* Lp4 = (s16x4*)Lp;
#pragma unroll
  for (int fm = 0; fm < 8; ++fm)
#pragma unroll
    for (int fn = 0; fn < 4; ++fn) {
      s16x4 pk;
      pk[0] = f2b(acc[fm][fn][0]);
      pk[1] = f2b(acc[fm][fn][1]);
      pk[2] = f2b(acc[fm][fn][2]);
      pk[3] = f2b(acc[fm][fn][3]);
      Lp4[pkb + (fm * 4 + fn) * 64] = pk;
    }
}

// ---------------- Z reduction: Z[r] = log(sum_cb Zpart[r][cb]) ------------
__global__ __launch_bounds__(256) void zred(const float* __restrict__ Zpart,
                                            float* __restrict__ Z) {
  const int tid = threadIdx.x;
  const int row = blockIdx.x * 64 + (tid >> 2);
  const int part = tid & 3;
  const float* p = Zpart + (size_t)row * 500 + part;
  float s = 0.f;
#pragma unroll 5
  for (int i = 0; i < 125; ++i) s += p[i * 4];
  s += __shfl_xor(s, 1);
  s += __shfl_xor(s, 2);
  if (part == 0) Z[row] = __logf(s);
}

// ---------------- coalesced single-pass JSD over the pack layout ----------
__global__ __launch_bounds__(256) void rows_jsd(
    const unsigned long long* __restrict__ Ls,
    const unsigned long long* __restrict__ Lt,
    const float* __restrict__ Z,
    float* __restrict__ partials) {
  __shared__ float zs[4096];
  const int tid = threadIdx.x;
  for (int i = tid; i < 1024; i += 256)
    ((float4*)zs)[i] = ((const float4*)Z)[i];
  __syncthreads();

  typedef __attribute__((ext_vector_type(2))) unsigned long long u64x2;
  const unsigned total = (unsigned)N_TOK * V_DIM / 8;  // 16B units
  float acc = 0.f;
  for (unsigned u = blockIdx.x * 256 + tid; u < total; u += gridDim.x * 256) {
    const unsigned e = u * 2;
    const unsigned pb = e >> 11;
    const unsigned mv = pb >> 3, wave = pb & 7;
    const unsigned mblk = mv / 125;
    const unsigned fm = (e >> 8) & 7, q = (e >> 4) & 3;
    const unsigned row0 = mblk * 256 + (wave >> 2) * 128 + fm * 16 + q * 4;
    const float4 zq = *(const float4*)&zs[row0];
    const float4 zp = *(const float4*)&zs[2048 + row0];
    u64x2 xs = *(const u64x2*)(Ls + e);
    u64x2 xt = *(const u64x2*)(Lt + e);
#pragma unroll
    for (int h = 0; h < 2; ++h) {
      const unsigned long long ws = xs[h], wt = xt[h];
#pragma unroll
      for (int j = 0; j < 4; ++j) {
        const float zqj = (j == 0) ? zq.x : (j == 1) ? zq.y : (j == 2) ? zq.z : zq.w;
        const float zpj = (j == 0) ? zp.x : (j == 1) ? zp.y : (j == 2) ? zp.z : zp.w;
        float lq = bf2f((short)(ws >> (16 * j))) - zqj;
        float lp = bf2f((short)(wt >> (16 * j))) - zpj;
        float qq = __expf(lq), pp = __expf(lp);
        float mm = pp + 0.5f * (qq - pp);
        float lm = __logf(mm);
        acc += 0.5f * (pp * (lp - lm)) + 0.5f * (qq * (lq - lm));
      }
    }
  }
#pragma unroll
  for (int o = 32; o; o >>= 1) acc += __shfl_xor(acc, o);
  __shared__ float red[4];
  const int wv = tid >> 6, ln = tid & 63;
  if (ln == 0) red[wv] = acc;
  __syncthreads();
  if (tid == 0) partials[blockIdx.x] = red[0] + red[1] + red[2] + red[3];
}

__global__ __launch_bounds__(256) void final_reduce(const float* __restrict__ partials,
                                                    int nb, float* __restrict__ out) {
  float s = 0.f;
  for (int i = threadIdx.x; i < nb; i += 256) s += partials[i];
#pragma unroll
  for (int o = 32; o; o >>= 1) s += __shfl_xor(s, o);
  __shared__ float red[4];
  if ((threadIdx.x & 63) == 0) red[threadIdx.x >> 6] = s;
  __syncthreads();
  if (threadIdx.x == 0) out[0] = (red[0] + red[1] + red[2] + red[3]) / (float)N_TOK;
}

// ---------------- launch ---------------------------------------------------
extern "C" void kernel_launch(void* const* d_in, const int* in_sizes, int n_in,
                              void* d_out, int out_size, void* d_ws, size_t ws_size,
                              hipStream_t stream) {
  const float* s_in = (const float*)d_in[0];
  const float* t_in = (const float*)d_in[1];
  const float* w_s  = (const float*)d_in[2];
  const float* w_t  = (const float*)d_in[3];
  float* out = (float*)d_out;

  char* ws = (char*)d_ws;
  size_t off = 0;
  auto alloc = [&](size_t bytes) {
    char* p = ws + off;
    off += (bytes + 255) & ~(size_t)255;
    return p;
  };
  short* Abf_s = (short*)alloc((size_t)N_TOK * H_DIM * 2);
  short* Abf_t = (short*)alloc((size_t)N_TOK * H_DIM * 2);
  unsigned long long* Lg_s = (unsigned long long*)alloc((size_t)N_TOK * V_DIM * 2);
  unsigned long long* Lg_t = (unsigned long long*)alloc((size_t)N_TOK * V_DIM * 2);
  float* Zpart = (float*)alloc((size_t)2 * 2048 * 500 * 4);
  float* Z     = (float*)alloc(4096 * 4);
  float* partials = (float*)alloc(2048 * 4);

  if (off > ws_size) {
    hipMemsetAsync(d_out, 0xFF, sizeof(float), stream);
    return;
  }

  cvt_in<<<512, 256, 0, stream>>>(s_in, t_in, Abf_s, Abf_t);

  gemm_logits<<<2000, 512, 0, stream>>>(Abf_s, Abf_t, w_s, w_t,
                                        Lg_s, Lg_t, Zpart);

  zred<<<64, 256, 0, stream>>>(Zpart, Z);
  rows_jsd<<<2048, 256, 0, stream>>>(Lg_s, Lg_t, Z, partials);
  final_reduce<<<1, 256, 0, stream>>>(partials, 2048, out);
}

// Round 12
// 703.094 us; speedup vs baseline: 1.0746x; 1.0746x over previous
//
#include <hip/hip_runtime.h>
#include <hip/hip_bf16.h>

#define N_TOK 2048
#define H_DIM 2048
#define V_DIM 32000

typedef __attribute__((ext_vector_type(8))) short short8;
typedef __attribute__((ext_vector_type(4))) short s16x4;
typedef __attribute__((ext_vector_type(4))) float f32x4;

__device__ __forceinline__ float bf2f(short s) {
  unsigned int u = ((unsigned int)(unsigned short)s) << 16;
  return __uint_as_float(u);
}
__device__ __forceinline__ short f2b(float f) {
  __hip_bfloat16 h = __float2bfloat16(f);
  return *reinterpret_cast<short*>(&h);
}

// ---------------- fp32 -> bf16 conversion (all 4 arrays, one launch) ------
__global__ __launch_bounds__(256) void cvt_all(
    const float* __restrict__ s0, const float* __restrict__ s1,
    const float* __restrict__ s2, const float* __restrict__ s3,
    short* __restrict__ d0, short* __restrict__ d1,
    short* __restrict__ d2, short* __restrict__ d3) {
  const int b = blockIdx.x;
  const float* s; short* d; int n8, b0, nb;
  if (b < 256)       { s = s0; d = d0; n8 = N_TOK * H_DIM / 8; b0 = b;        nb = 256;  }
  else if (b < 512)  { s = s1; d = d1; n8 = N_TOK * H_DIM / 8; b0 = b - 256;  nb = 256;  }
  else if (b < 2560) { s = s2; d = d2; n8 = V_DIM * H_DIM / 8; b0 = b - 512;  nb = 2048; }
  else               { s = s3; d = d3; n8 = V_DIM * H_DIM / 8; b0 = b - 2560; nb = 2048; }
  for (int i = b0 * 256 + threadIdx.x; i < n8; i += nb * 256) {
    const float4* sp = reinterpret_cast<const float4*>(s) + (size_t)i * 2;
    float4 a = sp[0], c = sp[1];
    short8 o;
    o[0] = f2b(a.x); o[1] = f2b(a.y); o[2] = f2b(a.z); o[3] = f2b(a.w);
    o[4] = f2b(c.x); o[5] = f2b(c.y); o[6] = f2b(c.z); o[7] = f2b(c.w);
    *reinterpret_cast<short8*>(d + (size_t)i * 8) = o;
  }
}

// ---------------- bf16 GEMM: logits[n,v] = sum_h A[n,h]*W[v,h] ------------
// r10 structure (best measured) with ONE change: the lgkmcnt(0)+
// sched_barrier(0) pin between ds_reads and MFMAs is REMOVED — plain-C
// ds_reads are dependency-tracked, so the compiler emits fine-grained
// lgkmcnt(N) and interleaves MFMAs under the read returns (phase-internal
// overlap). Phase-boundary ordering is still pinned by the end-of-phase
// sched_barrier(0)+s_barrier; staging schedule and vmcnt gates unchanged.
#define ASH 16384      // A shorts per buffer (256 rows x 64 cols)
#define BUF_SH 32768   // shorts per buffer (A + B)

__device__ __forceinline__ void gload_lds16(const void* g, void* l) {
  __builtin_amdgcn_global_load_lds(
      (const __attribute__((address_space(1))) void*)g,
      (__attribute__((address_space(3))) void*)l, 16, 0, 0);
}

#define STAGE_A(i, dst, kb) \
  gload_lds16(Aby + aoff##i + (kb), &lds[(dst) + (i) * 4096 + wbase])
#define STAGE_B(i, dst, kb) \
  gload_lds16(Wby + boff##i + (kb), &lds[(dst) + ASH + (i) * 4096 + wbase])

#define PHASE(KK, MH, GATE, ...) do {                                          \
    const int xorc = (((KK) * 4 + lk) ^ lr7) << 3;                             \
    short8 av0 = *(const short8*)&lds[cbase + aro + (MH)*4096 + 0    + xorc];  \
    short8 av1 = *(const short8*)&lds[cbase + aro + (MH)*4096 + 1024 + xorc];  \
    short8 av2 = *(const short8*)&lds[cbase + aro + (MH)*4096 + 2048 + xorc];  \
    short8 av3 = *(const short8*)&lds[cbase + aro + (MH)*4096 + 3072 + xorc];  \
    if ((MH) == 0) {                                                           \
      bv[0] = *(const short8*)&lds[cbase + bro + 0    + xorc];                 \
      bv[1] = *(const short8*)&lds[cbase + bro + 1024 + xorc];                 \
      bv[2] = *(const short8*)&lds[cbase + bro + 2048 + xorc];                 \
      bv[3] = *(const short8*)&lds[cbase + bro + 3072 + xorc];                 \
    }                                                                          \
    __VA_ARGS__                                                                \
    __builtin_amdgcn_s_setprio(1);                                             \
    acc[(MH)*4+0][0] = __builtin_amdgcn_mfma_f32_16x16x32_bf16(av0, bv[0], acc[(MH)*4+0][0],0,0,0); \
    acc[(MH)*4+0][1] = __builtin_amdgcn_mfma_f32_16x16x32_bf16(av0, bv[1], acc[(MH)*4+0][1],0,0,0); \
    acc[(MH)*4+0][2] = __builtin_amdgcn_mfma_f32_16x16x32_bf16(av0, bv[2], acc[(MH)*4+0][2],0,0,0); \
    acc[(MH)*4+0][3] = __builtin_amdgcn_mfma_f32_16x16x32_bf16(av0, bv[3], acc[(MH)*4+0][3],0,0,0); \
    acc[(MH)*4+1][0] = __builtin_amdgcn_mfma_f32_16x16x32_bf16(av1, bv[0], acc[(MH)*4+1][0],0,0,0); \
    acc[(MH)*4+1][1] = __builtin_amdgcn_mfma_f32_16x16x32_bf16(av1, bv[1], acc[(MH)*4+1][1],0,0,0); \
    acc[(MH)*4+1][2] = __builtin_amdgcn_mfma_f32_16x16x32_bf16(av1, bv[2], acc[(MH)*4+1][2],0,0,0); \
    acc[(MH)*4+1][3] = __builtin_amdgcn_mfma_f32_16x16x32_bf16(av1, bv[3], acc[(MH)*4+1][3],0,0,0); \
    acc[(MH)*4+2][0] = __builtin_amdgcn_mfma_f32_16x16x32_bf16(av2, bv[0], acc[(MH)*4+2][0],0,0,0); \
    acc[(MH)*4+2][1] = __builtin_amdgcn_mfma_f32_16x16x32_bf16(av2, bv[1], acc[(MH)*4+2][1],0,0,0); \
    acc[(MH)*4+2][2] = __builtin_amdgcn_mfma_f32_16x16x32_bf16(av2, bv[2], acc[(MH)*4+2][2],0,0,0); \
    acc[(MH)*4+2][3] = __builtin_amdgcn_mfma_f32_16x16x32_bf16(av2, bv[3], acc[(MH)*4+2][3],0,0,0); \
    acc[(MH)*4+3][0] = __builtin_amdgcn_mfma_f32_16x16x32_bf16(av3, bv[0], acc[(MH)*4+3][0],0,0,0); \
    acc[(MH)*4+3][1] = __builtin_amdgcn_mfma_f32_16x16x32_bf16(av3, bv[1], acc[(MH)*4+3][1],0,0,0); \
    acc[(MH)*4+3][2] = __builtin_amdgcn_mfma_f32_16x16x32_bf16(av3, bv[2], acc[(MH)*4+3][2],0,0,0); \
    acc[(MH)*4+3][3] = __builtin_amdgcn_mfma_f32_16x16x32_bf16(av3, bv[3], acc[(MH)*4+3][3],0,0,0); \
    __builtin_amdgcn_s_setprio(0);                                             \
    if ((GATE) == 2) asm volatile("s_waitcnt vmcnt(2)" ::: "memory");          \
    if ((GATE) == 0) asm volatile("s_waitcnt vmcnt(0)" ::: "memory");          \
    __builtin_amdgcn_sched_barrier(0);                                         \
    __builtin_amdgcn_s_barrier();                                              \
  } while (0)

__global__ __launch_bounds__(512, 2) void gemm_logits(
    const short* __restrict__ As, const short* __restrict__ At,
    const short* __restrict__ Ws, const short* __restrict__ Wt,
    unsigned long long* __restrict__ Lgs, unsigned long long* __restrict__ Lgt,
    float* __restrict__ Zpart) {
  __shared__ short lds[2 * BUF_SH];  // 128 KiB

  const int gid = blockIdx.x;
  const int swz = (gid & 7) * 250 + (gid >> 3);
  const int gemm = swz >= 1000;
  const int rem = swz - gemm * 1000;
  const int vblk = rem >> 3, mblk = rem & 7;
  const short* A = gemm ? At : As;
  const short* W = gemm ? Wt : Ws;
  unsigned long long* Lp = gemm ? Lgt : Lgs;
  const int m0 = mblk * 256, v0 = vblk * 256;

  const int tid = threadIdx.x;
  const int wave = tid >> 6, lane = tid & 63;
  const int lrow = lane & 15, lk = lane >> 4, lr7 = lrow & 7;
  const int wr = wave >> 2, wc = wave & 3;
  const int wbase = wave * 512;
  const int aro = (wr * 128 + lrow) * 64;
  const int bro = ASH + (wc * 64 + lrow) * 64;
  const char* Aby = (const char*)A;
  const char* Wby = (const char*)W;

  unsigned aoff0, aoff1, aoff2, aoff3, boff0, boff1, boff2, boff3;
  {
#define MKOFF(i, dstA, dstB)                                                   \
    {                                                                          \
      int g = (i) * 512 + wave * 64 + lane;                                    \
      int row = g >> 3, c8p = g & 7, col = (c8p ^ (row & 7)) << 3;             \
      dstA = (unsigned)((((m0) + row) * H_DIM + col) * 2);                     \
      dstB = (unsigned)((((v0) + row) * H_DIM + col) * 2);                     \
    }
    MKOFF(0, aoff0, boff0) MKOFF(1, aoff1, boff1)
    MKOFF(2, aoff2, boff2) MKOFF(3, aoff3, boff3)
#undef MKOFF
  }

  f32x4 acc[8][4];
#pragma unroll
  for (int i = 0; i < 8; ++i)
#pragma unroll
    for (int j = 0; j < 4; ++j) acc[i][j] = (f32x4){0.f, 0.f, 0.f, 0.f};
  short8 bv[4];

  // Prologue: tile0 fully (8) + A0,A2 of tile1 (2); vmcnt(2) leaves A0,A2
  // of tile1 in flight (steady-state invariant).
  STAGE_A(0, 0, 0); STAGE_A(2, 0, 0);
  STAGE_B(0, 0, 0); STAGE_B(1, 0, 0); STAGE_B(2, 0, 0); STAGE_B(3, 0, 0);
  STAGE_A(1, 0, 0); STAGE_A(3, 0, 0);
  STAGE_A(0, BUF_SH, 128); STAGE_A(2, BUF_SH, 128);
  asm volatile("s_waitcnt vmcnt(2)" ::: "memory");
  __builtin_amdgcn_sched_barrier(0);
  __builtin_amdgcn_s_barrier();

  for (int t = 0; t < 30; ++t) {
    const int cbase = (t & 1) * BUF_SH, nbase = cbase ^ BUF_SH;
    const int kbn = (t + 1) * 128, kbc = (t + 2) * 128;
    PHASE(0, 0, -1, STAGE_B(0, nbase, kbn); STAGE_B(1, nbase, kbn);
                    STAGE_B(2, nbase, kbn); STAGE_B(3, nbase, kbn););
    PHASE(0, 1, -1, STAGE_A(1, nbase, kbn); STAGE_A(3, nbase, kbn););
    PHASE(1, 0, -1, (void)0;);
    PHASE(1, 1,  2, STAGE_A(0, cbase, kbc); STAGE_A(2, cbase, kbc););
  }
  { const int cbase = 0, nbase = BUF_SH, kbn = 31 * 128;
    PHASE(0, 0, -1, STAGE_B(0, nbase, kbn); STAGE_B(1, nbase, kbn);
                    STAGE_B(2, nbase, kbn); STAGE_B(3, nbase, kbn););
    PHASE(0, 1, -1, STAGE_A(1, nbase, kbn); STAGE_A(3, nbase, kbn););
    PHASE(1, 0, -1, (void)0;);
    PHASE(1, 1,  0, (void)0;);
  }
  { const int cbase = BUF_SH;
    PHASE(0, 0, -1, (void)0;);
    PHASE(0, 1, -1, (void)0;);
    PHASE(1, 0, -1, (void)0;);
    PHASE(1, 1, -1, (void)0;);
  }

  // ---- Epilogue A: per-row sum-of-exp over this wave's 64 columns --------
  {
    const int q = lane >> 4;
    const int zb = (gemm * 2048 + mblk * 256 + wr * 128) * 500 + vblk * 4 + wc;
#pragma unroll
    for (int fm = 0; fm < 8; ++fm) {
#pragma unroll
      for (int j = 0; j < 4; ++j) {
        float s = __expf(acc[fm][0][j]) + __expf(acc[fm][1][j]) +
                  __expf(acc[fm][2][j]) + __expf(acc[fm][3][j]);
        s += __shfl_xor(s, 8);
        s += __shfl_xor(s, 4);
        s += __shfl_xor(s, 2);
        s += __shfl_xor(s, 1);
        if ((lane & 15) == 0)
          Zpart[zb + (fm * 16 + q * 4 + j) * 500] = s;
      }
    }
  }

  // ---- Epilogue B: pack-layout bf16 logits store (r5-verified) -----------
  const size_t pkb = ((size_t)(mblk * 125 + vblk) * 8 + wave) * 2048 + lane;
  s16x4* Lp4 = (s16x4*)Lp;
#pragma unroll
  for (int fm = 0; fm < 8; ++fm)
#pragma unroll
    for (int fn = 0; fn < 4; ++fn) {
      s16x4 pk;
      pk[0] = f2b(acc[fm][fn][0]);
      pk[1] = f2b(acc[fm][fn][1]);
      pk[2] = f2b(acc[fm][fn][2]);
      pk[3] = f2b(acc[fm][fn][3]);
      Lp4[pkb + (fm * 4 + fn) * 64] = pk;
    }
}

// ---------------- Z reduction: Z[r] = log(sum_cb Zpart[r][cb]) ------------
__global__ __launch_bounds__(256) void zred(const float* __restrict__ Zpart,
                                            float* __restrict__ Z) {
  const int tid = threadIdx.x;
  const int row = blockIdx.x * 64 + (tid >> 2);
  const int part = tid & 3;
  const float* p = Zpart + (size_t)row * 500 + part;
  float s = 0.f;
#pragma unroll 5
  for (int i = 0; i < 125; ++i) s += p[i * 4];
  s += __shfl_xor(s, 1);
  s += __shfl_xor(s, 2);
  if (part == 0) Z[row] = __logf(s);
}

// ---------------- coalesced single-pass JSD over the pack layout ----------
__global__ __launch_bounds__(256) void rows_jsd(
    const unsigned long long* __restrict__ Ls,
    const unsigned long long* __restrict__ Lt,
    const float* __restrict__ Z,
    float* __restrict__ partials) {
  __shared__ float zs[4096];
  const int tid = threadIdx.x;
  for (int i = tid; i < 1024; i += 256)
    ((float4*)zs)[i] = ((const float4*)Z)[i];
  __syncthreads();

  typedef __attribute__((ext_vector_type(2))) unsigned long long u64x2;
  const unsigned total = (unsigned)N_TOK * V_DIM / 8;  // 16B units
  float acc = 0.f;
  for (unsigned u = blockIdx.x * 256 + tid; u < total; u += gridDim.x * 256) {
    const unsigned e = u * 2;
    const unsigned pb = e >> 11;
    const unsigned mv = pb >> 3, wave = pb & 7;
    const unsigned mblk = mv / 125;
    const unsigned fm = (e >> 8) & 7, q = (e >> 4) & 3;
    const unsigned row0 = mblk * 256 + (wave >> 2) * 128 + fm * 16 + q * 4;
    const float4 zq = *(const float4*)&zs[row0];
    const float4 zp = *(const float4*)&zs[2048 + row0];
    u64x2 xs = *(const u64x2*)(Ls + e);
    u64x2 xt = *(const u64x2*)(Lt + e);
#pragma unroll
    for (int h = 0; h < 2; ++h) {
      const unsigned long long ws = xs[h], wt = xt[h];
#pragma unroll
      for (int j = 0; j < 4; ++j) {
        const float zqj = (j == 0) ? zq.x : (j == 1) ? zq.y : (j == 2) ? zq.z : zq.w;
        const float zpj = (j == 0) ? zp.x : (j == 1) ? zp.y : (j == 2) ? zp.z : zp.w;
        float lq = bf2f((short)(ws >> (16 * j))) - zqj;
        float lp = bf2f((short)(wt >> (16 * j))) - zpj;
        float qq = __expf(lq), pp = __expf(lp);
        float mm = pp + 0.5f * (qq - pp);
        float lm = __logf(mm);
        acc += 0.5f * (pp * (lp - lm)) + 0.5f * (qq * (lq - lm));
      }
    }
  }
#pragma unroll
  for (int o = 32; o; o >>= 1) acc += __shfl_xor(acc, o);
  __shared__ float red[4];
  const int wv = tid >> 6, ln = tid & 63;
  if (ln == 0) red[wv] = acc;
  __syncthreads();
  if (tid == 0) partials[blockIdx.x] = red[0] + red[1] + red[2] + red[3];
}

__global__ __launch_bounds__(256) void final_reduce(const float* __restrict__ partials,
                                                    int nb, float* __restrict__ out) {
  float s = 0.f;
  for (int i = threadIdx.x; i < nb; i += 256) s += partials[i];
#pragma unroll
  for (int o = 32; o; o >>= 1) s += __shfl_xor(s, o);
  __shared__ float red[4];
  if ((threadIdx.x & 63) == 0) red[threadIdx.x >> 6] = s;
  __syncthreads();
  if (threadIdx.x == 0) out[0] = (red[0] + red[1] + red[2] + red[3]) / (float)N_TOK;
}

// ---------------- launch ---------------------------------------------------
extern "C" void kernel_launch(void* const* d_in, const int* in_sizes, int n_in,
                              void* d_out, int out_size, void* d_ws, size_t ws_size,
                              hipStream_t stream) {
  const float* s_in = (const float*)d_in[0];
  const float* t_in = (const float*)d_in[1];
  const float* w_s  = (const float*)d_in[2];
  const float* w_t  = (const float*)d_in[3];
  float* out = (float*)d_out;

  char* ws = (char*)d_ws;
  size_t off = 0;
  auto alloc = [&](size_t bytes) {
    char* p = ws + off;
    off += (bytes + 255) & ~(size_t)255;
    return p;
  };
  short* Abf_s = (short*)alloc((size_t)N_TOK * H_DIM * 2);
  short* Abf_t = (short*)alloc((size_t)N_TOK * H_DIM * 2);
  short* Wbf_s = (short*)alloc((size_t)V_DIM * H_DIM * 2);
  short* Wbf_t = (short*)alloc((size_t)V_DIM * H_DIM * 2);
  unsigned long long* Lg_s = (unsigned long long*)alloc((size_t)N_TOK * V_DIM * 2);
  unsigned long long* Lg_t = (unsigned long long*)alloc((size_t)N_TOK * V_DIM * 2);
  float* Zpart = (float*)alloc((size_t)2 * 2048 * 500 * 4);
  float* Z     = (float*)alloc(4096 * 4);
  float* partials = (float*)alloc(2048 * 4);

  if (off > ws_size) {
    hipMemsetAsync(d_out, 0xFF, sizeof(float), stream);
    return;
  }

  cvt_all<<<4608, 256, 0, stream>>>(s_in, t_in, w_s, w_t,
                                    Abf_s, Abf_t, Wbf_s, Wbf_t);

  gemm_logits<<<2000, 512, 0, stream>>>(Abf_s, Abf_t, Wbf_s, Wbf_t,
                                        Lg_s, Lg_t, Zpart);

  zred<<<64, 256, 0, stream>>>(Zpart, Z);
  rows_jsd<<<2048, 256, 0, stream>>>(Lg_s, Lg_t, Z, partials);
  final_reduce<<<1, 256, 0, stream>>>(partials, 2048, out);
}